// Round 1
// baseline (13.311 us; speedup 1.0000x reference)
//
#include <hip/hip_runtime.h>

// WeightedCenterLoss:
//   c = centers[labels]                       (gather, B x D)
//   d = ||x||^2 + ||c||^2 - 2 x.c             (B,)
//   v = clip(d * class_weights[labels], 1e-12, 1e12)
//   loss = (sum(v) + B*(C-1)*1e-12) / B       (scalar)
//
// B=2048, D=256, C=50000. ~4.2 MB of reads -> latency/launch bound.
// One 64-lane wave per sample: 64 lanes x float4 == one 1KB row, fully
// coalesced. Deterministic 2-stage reduction (no float atomics).

constexpr int B = 2048;
constexpr int D = 256;
constexpr int C = 50000;

__global__ __launch_bounds__(256) void wcl_persample(
    const float* __restrict__ x, const float* __restrict__ centers,
    const float* __restrict__ cw, const int* __restrict__ labels,
    float* __restrict__ partial) {
  const int lane = threadIdx.x & 63;
  const int wave = (int)((blockIdx.x * blockDim.x + threadIdx.x) >> 6);
  if (wave >= B) return;

  const int lbl = labels[wave];
  const float4 xv = reinterpret_cast<const float4*>(x + (size_t)wave * D)[lane];
  const float4 cv = reinterpret_cast<const float4*>(centers + (size_t)lbl * D)[lane];

  const float xx = xv.x * xv.x + xv.y * xv.y + xv.z * xv.z + xv.w * xv.w;
  const float cc = cv.x * cv.x + cv.y * cv.y + cv.z * cv.z + cv.w * cv.w;
  const float xc = xv.x * cv.x + xv.y * cv.y + xv.z * cv.z + xv.w * cv.w;
  float s = xx + cc - 2.0f * xc;

#pragma unroll
  for (int off = 32; off > 0; off >>= 1) s += __shfl_xor(s, off, 64);

  if (lane == 0) {
    float v = s * cw[lbl];
    v = fminf(fmaxf(v, 1e-12f), 1e12f);
    partial[wave] = v;
  }
}

__global__ __launch_bounds__(256) void wcl_reduce(
    const float* __restrict__ partial, float* __restrict__ out) {
  __shared__ float sdata[4];
  float s = 0.0f;
  for (int i = threadIdx.x; i < B; i += 256) s += partial[i];
#pragma unroll
  for (int off = 32; off > 0; off >>= 1) s += __shfl_xor(s, off, 64);
  const int wid = (int)(threadIdx.x >> 6);
  if ((threadIdx.x & 63) == 0) sdata[wid] = s;
  __syncthreads();
  if (threadIdx.x == 0) {
    const float tot = sdata[0] + sdata[1] + sdata[2] + sdata[3];
    const float off_const = (float)((double)B * (double)(C - 1)) * 1e-12f;
    out[0] = (tot + off_const) / (float)B;
  }
}

extern "C" void kernel_launch(void* const* d_in, const int* in_sizes, int n_in,
                              void* d_out, int out_size, void* d_ws, size_t ws_size,
                              hipStream_t stream) {
  const float* x       = (const float*)d_in[0];
  const float* centers = (const float*)d_in[1];
  const float* cw      = (const float*)d_in[2];
  const int*   labels  = (const int*)d_in[3];
  float* out = (float*)d_out;
  float* partial = (float*)d_ws;  // 2048 floats = 8 KB scratch

  // One wave (64 lanes) per sample -> B/4 = 512 blocks of 256 threads.
  wcl_persample<<<(B * 64) / 256, 256, 0, stream>>>(x, centers, cw, labels, partial);
  wcl_reduce<<<1, 256, 0, stream>>>(partial, out);
}